// Round 8
// baseline (99.153 us; speedup 1.0000x reference)
//
#include <hip/hip_runtime.h>
#include <hip/hip_bf16.h>

#define NROW 4096      // 2B
#define HALFB 2048     // B
#define CDIM 1024
#define INV_T 2.0f     // 1/0.5
#define NBLK 32        // NROW / 128
#define NTRI 528       // NBLK*(NBLK+1)/2
#define NT 8           // CDIM / 128 K-tiles

typedef __attribute__((ext_vector_type(4))) float f32x4;
typedef __attribute__((ext_vector_type(8))) int i32x8;

// ---------------- Kernel 1: row L2-normalize + fp8(e4m3) pack (+ zero den) ----------------
__global__ __launch_bounds__(256) void normalize_kernel(
        const float* __restrict__ z1, const float* __restrict__ z2,
        unsigned int* __restrict__ zb8, float* __restrict__ den) {
    const int row = blockIdx.x;
    const int t = threadIdx.x;
    if (row < 16) den[row * 256 + t] = 0.f;   // NROW = 16*256; gemm is stream-ordered after
    const float* src = (row < HALFB) ? (z1 + (size_t)row * CDIM)
                                     : (z2 + (size_t)(row - HALFB) * CDIM);
    float4 v = ((const float4*)src)[t];
    float ss = v.x * v.x + v.y * v.y + v.z * v.z + v.w * v.w;
    #pragma unroll
    for (int off = 1; off < 64; off <<= 1) ss += __shfl_xor(ss, off);
    __shared__ float wsum[4];
    const int lane = t & 63, wv = t >> 6;
    if (lane == 0) wsum[wv] = ss;
    __syncthreads();
    const float tot = wsum[0] + wsum[1] + wsum[2] + wsum[3];
    const float scale = 1.0f / fmaxf(sqrtf(tot), 1e-12f);
    // pack 4 floats -> 4 e4m3 bytes (OCP, hardware cvt)
    int w = __builtin_amdgcn_cvt_pk_fp8_f32(v.x * scale, v.y * scale, 0, false);
    w = __builtin_amdgcn_cvt_pk_fp8_f32(v.z * scale, v.w * scale, w, true);
    zb8[(size_t)row * 256 + t] = (unsigned int)w;
}

// ---------------- Kernel 2: upper-triangle MX-fp8 GEMM + exp + row/col sums + pos ----------------
// 528 blocks (triangle of 128^2 tiles), 256 thr (4 waves 2x2, per-wave 64x64).
// K: 8 tiles of BK=128 via mfma_scale_f32_16x16x128_f8f6f4, unit scales (E8M0 127).
// Symmetry: block (bi,bj), bi<bj adds row-sums to den[i-panel] and col-sums to
// den[j-panel]; diag blocks stage A only, row-sums only.
// LDS swizzle: 16B chunk c of row r holds global chunk c^(r&7); applied on the
// gload_lds SOURCE (linear LDS dest) and on ds_read (rule 21).
// Rule #20: all acc indices compile-time.
__global__ __launch_bounds__(256, 2) void gemm_den_kernel(
        const unsigned char* __restrict__ zb8, float* __restrict__ den,
        float* __restrict__ pos) {
    __shared__ __align__(16) unsigned char As[128 * 128];
    __shared__ __align__(16) unsigned char Bs[128 * 128];

    // XCD swizzle (528 = 8*66, bijective), then triangle decode
    const int orig = blockIdx.x;
    int swz = (orig & 7) * (NTRI / 8) + (orig >> 3);
    int bi = 0, rem = swz;
    while (rem >= NBLK - bi) { rem -= NBLK - bi; ++bi; }
    const int bj = bi + rem;
    const int i0 = bi * 128, j0 = bj * 128;
    const bool diag = (bi == bj);
    const bool is_pos = (bj == bi + 16);   // holds S[i, i+B] on its tile diagonal

    const int tid = threadIdx.x;
    const int wave = tid >> 6, lane = tid & 63;
    const int wr = wave >> 1, wc = wave & 1;

    f32x4 acc[4][4];
    #pragma unroll
    for (int m = 0; m < 4; m++)
        #pragma unroll
        for (int n = 0; n < 4; n++) acc[m][n] = (f32x4){0.f, 0.f, 0.f, 0.f};

    // staging geometry: one gload_lds = 8 rows x 128B; lane: row=lane>>3, chunk=lane&7
    const int srow = lane >> 3;                    // 0..7
    const int schunk = (lane & 7) ^ srow;          // pre-swizzled source 16B chunk

    const int l15 = lane & 15, ks = lane >> 4;

    for (int t = 0; t < NT; ++t) {
        const int kb = t * 128;
        #pragma unroll
        for (int c = 0; c < 4; ++c) {
            const int r0 = (wave * 4 + c) * 8;     // wave-uniform row base (0..120)
            const unsigned char* ga =
                zb8 + (size_t)(i0 + r0 + srow) * CDIM + kb + schunk * 16;
            __builtin_amdgcn_global_load_lds(
                (const __attribute__((address_space(1))) void*)ga,
                (__attribute__((address_space(3))) void*)(As + r0 * 128),
                16, 0, 0);
            if (!diag) {
                const unsigned char* gb =
                    zb8 + (size_t)(j0 + r0 + srow) * CDIM + kb + schunk * 16;
                __builtin_amdgcn_global_load_lds(
                    (const __attribute__((address_space(1))) void*)gb,
                    (__attribute__((address_space(3))) void*)(Bs + r0 * 128),
                    16, 0, 0);
            }
        }
        __syncthreads();
        const unsigned char* Bsrc = diag ? As : Bs;

        // fragments: per lane 32 bytes = k in [ks*32, ks*32+32), row = frag*16 + l15
        i32x8 a[4], b[4];
        #pragma unroll
        for (int m = 0; m < 4; ++m) {
            const int r = wr * 64 + m * 16 + l15;
            const int c0 = (2 * ks) ^ (r & 7);
            const int c1 = (2 * ks + 1) ^ (r & 7);
            const int4 lo = *(const int4*)(As + r * 128 + c0 * 16);
            const int4 hi = *(const int4*)(As + r * 128 + c1 * 16);
            a[m] = (i32x8){lo.x, lo.y, lo.z, lo.w, hi.x, hi.y, hi.z, hi.w};
        }
        #pragma unroll
        for (int n = 0; n < 4; ++n) {
            const int r = wc * 64 + n * 16 + l15;
            const int c0 = (2 * ks) ^ (r & 7);
            const int c1 = (2 * ks + 1) ^ (r & 7);
            const int4 lo = *(const int4*)(Bsrc + r * 128 + c0 * 16);
            const int4 hi = *(const int4*)(Bsrc + r * 128 + c1 * 16);
            b[n] = (i32x8){lo.x, lo.y, lo.z, lo.w, hi.x, hi.y, hi.z, hi.w};
        }
        __builtin_amdgcn_s_setprio(1);
        #pragma unroll
        for (int m = 0; m < 4; ++m)
            #pragma unroll
            for (int n = 0; n < 4; ++n)
                acc[m][n] = __builtin_amdgcn_mfma_scale_f32_16x16x128_f8f6f4(
                    a[m], b[n], acc[m][n],
                    0 /*cbsz: A=fp8*/, 0 /*blgp: B=fp8*/,
                    0, 127 /*scaleA = 2^0*/,
                    0, 127 /*scaleB = 2^0*/);
        __builtin_amdgcn_s_setprio(0);
        __syncthreads();
    }

    // ---- positives: tiles bj == bi+16 (bi<16) hold S[i, i+B] on their diagonal
    if (is_pos && wr == wc) {
        #pragma unroll
        for (int m = 0; m < 4; ++m) {
            #pragma unroll
            for (int r = 0; r < 4; ++r) {
                if (l15 == ks * 4 + r)
                    pos[i0 + wr * 64 + m * 16 + l15] = acc[m][m][r];
            }
        }
    }

    // ---- epilogue: e = exp(2*s); row-sums -> den[i-panel]; col-sums -> den[j-panel]
    float cs[4] = {0.f, 0.f, 0.f, 0.f};
    #pragma unroll
    for (int m = 0; m < 4; ++m) {
        #pragma unroll
        for (int r = 0; r < 4; ++r) {
            float rs = 0.f;
            #pragma unroll
            for (int n = 0; n < 4; ++n) {
                const float e = __expf(INV_T * acc[m][n][r]);
                rs += e;
                cs[n] += e;
            }
            rs += __shfl_xor(rs, 1);
            rs += __shfl_xor(rs, 2);
            rs += __shfl_xor(rs, 4);
            rs += __shfl_xor(rs, 8);
            if (l15 == 0) {
                const int grow = i0 + wr * 64 + m * 16 + ks * 4 + r;
                atomicAdd(&den[grow], rs);
            }
        }
    }
    if (!diag) {
        #pragma unroll
        for (int n = 0; n < 4; ++n) {
            float c = cs[n];
            c += __shfl_xor(c, 16);
            c += __shfl_xor(c, 32);
            if (lane < 16) {
                const int gcol = j0 + wc * 64 + n * 16 + lane;
                atomicAdd(&den[gcol], c);
            }
        }
    }
}

// ---------------- Kernel 3: final loss ----------------
__global__ __launch_bounds__(256) void loss_kernel(
        const float* __restrict__ den, const float* __restrict__ pos,
        float* __restrict__ out) {
    const float E2 = 7.3890560989306495f;  // exp(2) = diagonal term
    const int tid = threadIdx.x;
    float acc = 0.f;
    for (int i = tid; i < NROW; i += 256)
        acc += INV_T * pos[i & (HALFB - 1)] - logf(den[i] - E2);
    #pragma unroll
    for (int off = 1; off < 64; off <<= 1) acc += __shfl_xor(acc, off);
    __shared__ float wsum[4];
    const int lane = tid & 63, wv = tid >> 6;
    if (lane == 0) wsum[wv] = acc;
    __syncthreads();
    if (tid == 0) out[0] = -(wsum[0] + wsum[1] + wsum[2] + wsum[3]) * (1.0f / NROW);
}

extern "C" void kernel_launch(void* const* d_in, const int* in_sizes, int n_in,
                              void* d_out, int out_size, void* d_ws, size_t ws_size,
                              hipStream_t stream) {
    const float* z1 = (const float*)d_in[0];
    const float* z2 = (const float*)d_in[1];
    float* out = (float*)d_out;

    unsigned int* zb8 = (unsigned int*)d_ws;                         // 4 MB (fp8)
    float* den = (float*)((char*)d_ws + (size_t)NROW * CDIM);        // 16 KB
    float* pos = den + NROW;                                         // 8 KB

    normalize_kernel<<<NROW, 256, 0, stream>>>(z1, z2, zb8, den);
    gemm_den_kernel<<<NTRI, 256, 0, stream>>>((const unsigned char*)zb8, den, pos);
    loss_kernel<<<1, 256, 0, stream>>>(den, pos, out);
}

// Round 9
// 35.775 us; speedup vs baseline: 2.7716x; 2.7716x over previous
//
#include <hip/hip_runtime.h>
#include <hip/hip_bf16.h>

#define NROW 4096      // 2B
#define HALFB 2048     // B
#define CDIM 1024
#define INV_T 2.0f     // 1/0.5
#define NBLK 32        // NROW / 128
#define NTRI 528       // NBLK*(NBLK+1)/2
#define NT 8           // CDIM / 128 K-tiles

typedef __attribute__((ext_vector_type(4))) float f32x4;
typedef __attribute__((ext_vector_type(8))) int i32x8;

// ---------------- Kernel 1: row L2-normalize + fp8(e4m3) pack (+ zero den) ----------------
__global__ __launch_bounds__(256) void normalize_kernel(
        const float* __restrict__ z1, const float* __restrict__ z2,
        unsigned int* __restrict__ zb8, float* __restrict__ den) {
    const int row = blockIdx.x;
    const int t = threadIdx.x;
    if (row < 16) den[row * 256 + t] = 0.f;   // NROW = 16*256; gemm is stream-ordered after
    const float* src = (row < HALFB) ? (z1 + (size_t)row * CDIM)
                                     : (z2 + (size_t)(row - HALFB) * CDIM);
    float4 v = ((const float4*)src)[t];
    float ss = v.x * v.x + v.y * v.y + v.z * v.z + v.w * v.w;
    #pragma unroll
    for (int off = 1; off < 64; off <<= 1) ss += __shfl_xor(ss, off);
    __shared__ float wsum[4];
    const int lane = t & 63, wv = t >> 6;
    if (lane == 0) wsum[wv] = ss;
    __syncthreads();
    const float tot = wsum[0] + wsum[1] + wsum[2] + wsum[3];
    const float scale = 1.0f / fmaxf(sqrtf(tot), 1e-12f);
    // pack 4 floats -> 4 e4m3 bytes (OCP, hardware cvt)
    int w = __builtin_amdgcn_cvt_pk_fp8_f32(v.x * scale, v.y * scale, 0, false);
    w = __builtin_amdgcn_cvt_pk_fp8_f32(v.z * scale, v.w * scale, w, true);
    zb8[(size_t)row * 256 + t] = (unsigned int)w;
}

// ---------------- Kernel 2: upper-triangle MX-fp8 GEMM + exp + row/col sums + pos ----------------
// 528 blocks (triangle of 128^2 tiles), 256 thr (4 waves 2x2, per-wave 64x64).
// K: 8 tiles of BK=128 via mfma_scale_f32_16x16x128_f8f6f4, unit scales (E8M0 127).
// Symmetry: block (bi,bj), bi<bj adds row-sums to den[i-panel] and col-sums to
// den[j-panel]; diag blocks stage the SAME panel into Bs (no pointer select, no
// staging branch -- R8's Bsrc select + reg pressure spilled 139MB to scratch).
// Register budget (rule #20 + R8 lesson): b[4]=32, a JIT-loaded per m (8), acc=64;
// no launch_bounds VGPR cap.
// LDS swizzle: 16B chunk c of row r holds global chunk c^(r&7); applied on the
// gload_lds SOURCE (linear LDS dest) and on ds_read (rule 21).
__global__ __launch_bounds__(256) void gemm_den_kernel(
        const unsigned char* __restrict__ zb8, float* __restrict__ den,
        float* __restrict__ pos) {
    __shared__ __align__(16) unsigned char As[128 * 128];
    __shared__ __align__(16) unsigned char Bs[128 * 128];

    // XCD swizzle (528 = 8*66, bijective), then triangle decode
    const int orig = blockIdx.x;
    int swz = (orig & 7) * (NTRI / 8) + (orig >> 3);
    int bi = 0, rem = swz;
    while (rem >= NBLK - bi) { rem -= NBLK - bi; ++bi; }
    const int bj = bi + rem;
    const int i0 = bi * 128, j0 = bj * 128;
    const bool diag = (bi == bj);
    const bool is_pos = (bj == bi + 16);   // holds S[i, i+B] on its tile diagonal

    const int tid = threadIdx.x;
    const int wave = tid >> 6, lane = tid & 63;
    const int wr = wave >> 1, wc = wave & 1;

    f32x4 acc[4][4];
    #pragma unroll
    for (int m = 0; m < 4; m++)
        #pragma unroll
        for (int n = 0; n < 4; n++) acc[m][n] = (f32x4){0.f, 0.f, 0.f, 0.f};

    // staging geometry: one gload_lds = 8 rows x 128B; lane: row=lane>>3, chunk=lane&7
    const int srow = lane >> 3;                    // 0..7
    const int schunk = (lane & 7) ^ srow;          // pre-swizzled source 16B chunk

    const int l15 = lane & 15, ks = lane >> 4;

    for (int t = 0; t < NT; ++t) {
        const int kb = t * 128;
        #pragma unroll
        for (int c = 0; c < 4; ++c) {
            const int r0 = (wave * 4 + c) * 8;     // wave-uniform row base (0..120)
            const unsigned char* ga =
                zb8 + (size_t)(i0 + r0 + srow) * CDIM + kb + schunk * 16;
            __builtin_amdgcn_global_load_lds(
                (const __attribute__((address_space(1))) void*)ga,
                (__attribute__((address_space(3))) void*)(As + r0 * 128),
                16, 0, 0);
            // diag blocks: j0 == i0 -> stages the same panel (uniform schedule)
            const unsigned char* gb =
                zb8 + (size_t)(j0 + r0 + srow) * CDIM + kb + schunk * 16;
            __builtin_amdgcn_global_load_lds(
                (const __attribute__((address_space(1))) void*)gb,
                (__attribute__((address_space(3))) void*)(Bs + r0 * 128),
                16, 0, 0);
        }
        __syncthreads();

        // fragments: per lane 32 bytes = k in [ks*32, ks*32+32), row = frag*16 + l15
        i32x8 b[4];
        #pragma unroll
        for (int n = 0; n < 4; ++n) {
            const int r = wc * 64 + n * 16 + l15;
            const int c0 = (2 * ks) ^ (r & 7);
            const int c1 = (2 * ks + 1) ^ (r & 7);
            const int4 lo = *(const int4*)(Bs + r * 128 + c0 * 16);
            const int4 hi = *(const int4*)(Bs + r * 128 + c1 * 16);
            b[n] = (i32x8){lo.x, lo.y, lo.z, lo.w, hi.x, hi.y, hi.z, hi.w};
        }
        __builtin_amdgcn_s_setprio(1);
        #pragma unroll
        for (int m = 0; m < 4; ++m) {
            const int r = wr * 64 + m * 16 + l15;
            const int c0 = (2 * ks) ^ (r & 7);
            const int c1 = (2 * ks + 1) ^ (r & 7);
            const int4 lo = *(const int4*)(As + r * 128 + c0 * 16);
            const int4 hi = *(const int4*)(As + r * 128 + c1 * 16);
            const i32x8 a = (i32x8){lo.x, lo.y, lo.z, lo.w, hi.x, hi.y, hi.z, hi.w};
            #pragma unroll
            for (int n = 0; n < 4; ++n)
                acc[m][n] = __builtin_amdgcn_mfma_scale_f32_16x16x128_f8f6f4(
                    a, b[n], acc[m][n],
                    0 /*cbsz: A=fp8*/, 0 /*blgp: B=fp8*/,
                    0, 127 /*scaleA = 2^0*/,
                    0, 127 /*scaleB = 2^0*/);
        }
        __builtin_amdgcn_s_setprio(0);
        __syncthreads();
    }

    // ---- positives: tiles bj == bi+16 (bi<16) hold S[i, i+B] on their diagonal
    if (is_pos && wr == wc) {
        #pragma unroll
        for (int m = 0; m < 4; ++m) {
            #pragma unroll
            for (int r = 0; r < 4; ++r) {
                if (l15 == ks * 4 + r)
                    pos[i0 + wr * 64 + m * 16 + l15] = acc[m][m][r];
            }
        }
    }

    // ---- epilogue: e = exp(2*s); row-sums -> den[i-panel]; col-sums -> den[j-panel]
    float cs[4] = {0.f, 0.f, 0.f, 0.f};
    #pragma unroll
    for (int m = 0; m < 4; ++m) {
        #pragma unroll
        for (int r = 0; r < 4; ++r) {
            float rs = 0.f;
            #pragma unroll
            for (int n = 0; n < 4; ++n) {
                const float e = __expf(INV_T * acc[m][n][r]);
                rs += e;
                cs[n] += e;
            }
            rs += __shfl_xor(rs, 1);
            rs += __shfl_xor(rs, 2);
            rs += __shfl_xor(rs, 4);
            rs += __shfl_xor(rs, 8);
            if (l15 == 0) {
                const int grow = i0 + wr * 64 + m * 16 + ks * 4 + r;
                atomicAdd(&den[grow], rs);
            }
        }
    }
    if (!diag) {
        #pragma unroll
        for (int n = 0; n < 4; ++n) {
            float c = cs[n];
            c += __shfl_xor(c, 16);
            c += __shfl_xor(c, 32);
            if (lane < 16) {
                const int gcol = j0 + wc * 64 + n * 16 + lane;
                atomicAdd(&den[gcol], c);
            }
        }
    }
}

// ---------------- Kernel 3: final loss ----------------
__global__ __launch_bounds__(256) void loss_kernel(
        const float* __restrict__ den, const float* __restrict__ pos,
        float* __restrict__ out) {
    const float E2 = 7.3890560989306495f;  // exp(2) = diagonal term
    const int tid = threadIdx.x;
    float acc = 0.f;
    for (int i = tid; i < NROW; i += 256)
        acc += INV_T * pos[i & (HALFB - 1)] - logf(den[i] - E2);
    #pragma unroll
    for (int off = 1; off < 64; off <<= 1) acc += __shfl_xor(acc, off);
    __shared__ float wsum[4];
    const int lane = tid & 63, wv = tid >> 6;
    if (lane == 0) wsum[wv] = acc;
    __syncthreads();
    if (tid == 0) out[0] = -(wsum[0] + wsum[1] + wsum[2] + wsum[3]) * (1.0f / NROW);
}

extern "C" void kernel_launch(void* const* d_in, const int* in_sizes, int n_in,
                              void* d_out, int out_size, void* d_ws, size_t ws_size,
                              hipStream_t stream) {
    const float* z1 = (const float*)d_in[0];
    const float* z2 = (const float*)d_in[1];
    float* out = (float*)d_out;

    unsigned int* zb8 = (unsigned int*)d_ws;                         // 4 MB (fp8)
    float* den = (float*)((char*)d_ws + (size_t)NROW * CDIM);        // 16 KB
    float* pos = den + NROW;                                         // 8 KB

    normalize_kernel<<<NROW, 256, 0, stream>>>(z1, z2, zb8, den);
    gemm_den_kernel<<<NTRI, 256, 0, stream>>>((const unsigned char*)zb8, den, pos);
    loss_kernel<<<1, 256, 0, stream>>>(den, pos, out);
}

// Round 10
// 33.211 us; speedup vs baseline: 2.9855x; 1.0772x over previous
//
#include <hip/hip_runtime.h>
#include <hip/hip_bf16.h>

#define NROW 4096      // 2B
#define HALFB 2048     // B
#define CDIM 1024
#define INV_T 2.0f     // 1/0.5
#define NBLK 32        // NROW / 128
#define NTRI 528       // NBLK*(NBLK+1)/2
#define NT 8           // CDIM / 128 K-tiles
#define RB 512         // bytes per row in fp4 (1024 * 4bit)
#define SCALE_E8M0 122 // 2^-5: data stored as x*32 in e2m1; scale applied on A and B

typedef __attribute__((ext_vector_type(4))) float f32x4;
typedef __attribute__((ext_vector_type(8))) int i32x8;

// round-to-nearest e2m1 encode of q (|q| clamped to 6)
__device__ __forceinline__ unsigned enc_fp4(float q) {
    const unsigned s = q < 0.f ? 8u : 0u;
    const float a = fabsf(q);
    unsigned m;
    if (a < 1.25f) {
        if (a < 0.25f)      m = 0;   // 0.0
        else if (a < 0.75f) m = 1;   // 0.5
        else                m = 2;   // 1.0
    } else if (a < 2.5f) {
        m = (a < 1.75f) ? 3u : 4u;   // 1.5 : 2
    } else {
        if (a < 3.5f)       m = 5;   // 3
        else if (a < 5.0f)  m = 6;   // 4
        else                m = 7;   // 6
    }
    return s | m;
}

// ---------------- Kernel 1: row L2-normalize + fp4(e2m1) pack (+ zero den) ----------------
// q = 32 * x / ||x|| ~ N(0,1); stored e2m1, dequant by 2^-5 inside the MFMA.
__global__ __launch_bounds__(256) void normalize_kernel(
        const float* __restrict__ z1, const float* __restrict__ z2,
        unsigned short* __restrict__ zb4, float* __restrict__ den) {
    const int row = blockIdx.x;
    const int t = threadIdx.x;
    if (row < 16) den[row * 256 + t] = 0.f;   // NROW = 16*256; gemm is stream-ordered after
    const float* src = (row < HALFB) ? (z1 + (size_t)row * CDIM)
                                     : (z2 + (size_t)(row - HALFB) * CDIM);
    float4 v = ((const float4*)src)[t];
    float ss = v.x * v.x + v.y * v.y + v.z * v.z + v.w * v.w;
    #pragma unroll
    for (int off = 1; off < 64; off <<= 1) ss += __shfl_xor(ss, off);
    __shared__ float wsum[4];
    const int lane = t & 63, wv = t >> 6;
    if (lane == 0) wsum[wv] = ss;
    __syncthreads();
    const float tot = wsum[0] + wsum[1] + wsum[2] + wsum[3];
    const float scale = 32.0f / fmaxf(sqrtf(tot), 1e-12f);
    const unsigned c0 = enc_fp4(v.x * scale);
    const unsigned c1 = enc_fp4(v.y * scale);
    const unsigned c2 = enc_fp4(v.z * scale);
    const unsigned c3 = enc_fp4(v.w * scale);
    zb4[(size_t)row * 256 + t] = (unsigned short)(c0 | (c1 << 4) | (c2 << 8) | (c3 << 12));
}

// ---------------- Kernel 2: upper-triangle MX-fp4 GEMM + exp + row/col sums + pos ----------------
// 528 blocks (triangle of 128^2 tiles), 256 thr (4 waves 2x2, per-wave 64x64).
// K: 8 tiles of BK=128 via mfma_scale_f32_16x16x128_f8f6f4 FMT=fp4 (cbsz=blgp=4),
// uniform E8M0 scale 2^-5 on both operands (layout-free since uniform).
// Correctness note: S = Z Z^T is operand-symmetric, so any common k-permutation
// in the fp4 nibble/fragment layout cancels between A and B; only the row->lane
// mapping (l15) matters, identical to the verified fp8 kernel.
// LDS 16KB: As/Bs [128 rows x 64B]. Swizzle: 16B chunk c of row r holds global
// chunk c^((r>>1)&3) (pre-swizzled gload_lds SOURCE, linear dest; same XOR on
// ds_read -> net identity, 2-way residual bank aliasing = free).
// Register budget (R8 lesson): b[4]=32 regs, a JIT per m, acc=64; no VGPR cap.
__global__ __launch_bounds__(256) void gemm_den_kernel(
        const unsigned char* __restrict__ zb4, float* __restrict__ den,
        float* __restrict__ pos) {
    __shared__ __align__(16) unsigned char As[128 * 64];
    __shared__ __align__(16) unsigned char Bs[128 * 64];

    // XCD swizzle (528 = 8*66, bijective), then triangle decode
    const int orig = blockIdx.x;
    int swz = (orig & 7) * (NTRI / 8) + (orig >> 3);
    int bi = 0, rem = swz;
    while (rem >= NBLK - bi) { rem -= NBLK - bi; ++bi; }
    const int bj = bi + rem;
    const int i0 = bi * 128, j0 = bj * 128;
    const bool diag = (bi == bj);
    const bool is_pos = (bj == bi + 16);   // holds S[i, i+B] on its tile diagonal

    const int tid = threadIdx.x;
    const int wave = tid >> 6, lane = tid & 63;
    const int wr = wave >> 1, wc = wave & 1;

    f32x4 acc[4][4];
    #pragma unroll
    for (int m = 0; m < 4; m++)
        #pragma unroll
        for (int n = 0; n < 4; n++) acc[m][n] = (f32x4){0.f, 0.f, 0.f, 0.f};

    // staging geometry: one gload_lds = 16 rows x 64B; lane: row=lane>>2, chunk=lane&3
    const int srow = lane >> 2;                            // 0..15
    const int schunk = (lane & 3) ^ ((srow >> 1) & 3);     // pre-swizzled source chunk

    const int l15 = lane & 15, ks = lane >> 4;

    for (int t = 0; t < NT; ++t) {
        const int kb = t * 64;                 // byte offset of this K-tile in a row
        #pragma unroll
        for (int c = 0; c < 2; ++c) {
            const int r0 = wave * 32 + c * 16; // wave-uniform row base (0..112)
            const unsigned char* ga =
                zb4 + (size_t)(i0 + r0 + srow) * RB + kb + schunk * 16;
            __builtin_amdgcn_global_load_lds(
                (const __attribute__((address_space(1))) void*)ga,
                (__attribute__((address_space(3))) void*)(As + r0 * 64),
                16, 0, 0);
            // diag blocks: j0 == i0 -> stages the same panel (uniform schedule)
            const unsigned char* gb =
                zb4 + (size_t)(j0 + r0 + srow) * RB + kb + schunk * 16;
            __builtin_amdgcn_global_load_lds(
                (const __attribute__((address_space(1))) void*)gb,
                (__attribute__((address_space(3))) void*)(Bs + r0 * 64),
                16, 0, 0);
        }
        __syncthreads();

        // fragments: per lane 16B = 32 fp4 = k in [ks*32, ks*32+32), row = frag*16+l15
        i32x8 b[4];
        #pragma unroll
        for (int n = 0; n < 4; ++n) {
            const int r = wc * 64 + n * 16 + l15;
            const int slot = ks ^ ((r >> 1) & 3);
            const int4 w = *(const int4*)(Bs + r * 64 + slot * 16);
            b[n] = (i32x8){w.x, w.y, w.z, w.w, 0, 0, 0, 0};
        }
        __builtin_amdgcn_s_setprio(1);
        #pragma unroll
        for (int m = 0; m < 4; ++m) {
            const int r = wr * 64 + m * 16 + l15;
            const int slot = ks ^ ((r >> 1) & 3);
            const int4 w = *(const int4*)(As + r * 64 + slot * 16);
            const i32x8 a = (i32x8){w.x, w.y, w.z, w.w, 0, 0, 0, 0};
            #pragma unroll
            for (int n = 0; n < 4; ++n)
                acc[m][n] = __builtin_amdgcn_mfma_scale_f32_16x16x128_f8f6f4(
                    a, b[n], acc[m][n],
                    4 /*cbsz: A=fp4*/, 4 /*blgp: B=fp4*/,
                    0, SCALE_E8M0 /*scaleA = 2^-5*/,
                    0, SCALE_E8M0 /*scaleB = 2^-5*/);
        }
        __builtin_amdgcn_s_setprio(0);
        __syncthreads();
    }

    // ---- positives: tiles bj == bi+16 (bi<16) hold S[i, i+B] on their diagonal
    if (is_pos && wr == wc) {
        #pragma unroll
        for (int m = 0; m < 4; ++m) {
            #pragma unroll
            for (int r = 0; r < 4; ++r) {
                if (l15 == ks * 4 + r)
                    pos[i0 + wr * 64 + m * 16 + l15] = acc[m][m][r];
            }
        }
    }

    // ---- epilogue: e = exp(2*s); row-sums -> den[i-panel]; col-sums -> den[j-panel]
    float cs[4] = {0.f, 0.f, 0.f, 0.f};
    #pragma unroll
    for (int m = 0; m < 4; ++m) {
        #pragma unroll
        for (int r = 0; r < 4; ++r) {
            float rs = 0.f;
            #pragma unroll
            for (int n = 0; n < 4; ++n) {
                const float e = __expf(INV_T * acc[m][n][r]);
                rs += e;
                cs[n] += e;
            }
            rs += __shfl_xor(rs, 1);
            rs += __shfl_xor(rs, 2);
            rs += __shfl_xor(rs, 4);
            rs += __shfl_xor(rs, 8);
            if (l15 == 0) {
                const int grow = i0 + wr * 64 + m * 16 + ks * 4 + r;
                atomicAdd(&den[grow], rs);
            }
        }
    }
    if (!diag) {
        #pragma unroll
        for (int n = 0; n < 4; ++n) {
            float c = cs[n];
            c += __shfl_xor(c, 16);
            c += __shfl_xor(c, 32);
            if (lane < 16) {
                const int gcol = j0 + wc * 64 + n * 16 + lane;
                atomicAdd(&den[gcol], c);
            }
        }
    }
}

// ---------------- Kernel 3: final loss ----------------
__global__ __launch_bounds__(256) void loss_kernel(
        const float* __restrict__ den, const float* __restrict__ pos,
        float* __restrict__ out) {
    const float E2 = 7.3890560989306495f;  // exp(2) = diagonal term (quantized self-dot
                                           // deviation contributes ~1e-4 to the loss)
    const int tid = threadIdx.x;
    float acc = 0.f;
    for (int i = tid; i < NROW; i += 256)
        acc += INV_T * pos[i & (HALFB - 1)] - logf(den[i] - E2);
    #pragma unroll
    for (int off = 1; off < 64; off <<= 1) acc += __shfl_xor(acc, off);
    __shared__ float wsum[4];
    const int lane = tid & 63, wv = tid >> 6;
    if (lane == 0) wsum[wv] = acc;
    __syncthreads();
    if (tid == 0) out[0] = -(wsum[0] + wsum[1] + wsum[2] + wsum[3]) * (1.0f / NROW);
}

extern "C" void kernel_launch(void* const* d_in, const int* in_sizes, int n_in,
                              void* d_out, int out_size, void* d_ws, size_t ws_size,
                              hipStream_t stream) {
    const float* z1 = (const float*)d_in[0];
    const float* z2 = (const float*)d_in[1];
    float* out = (float*)d_out;

    unsigned short* zb4 = (unsigned short*)d_ws;                     // 2 MB (fp4)
    float* den = (float*)((char*)d_ws + (size_t)NROW * RB);          // 16 KB
    float* pos = den + NROW;                                         // 8 KB

    normalize_kernel<<<NROW, 256, 0, stream>>>(z1, z2, zb4, den);
    gemm_den_kernel<<<NTRI, 256, 0, stream>>>((const unsigned char*)zb4, den, pos);
    loss_kernel<<<1, 256, 0, stream>>>(den, pos, out);
}

// Round 11
// 33.207 us; speedup vs baseline: 2.9859x; 1.0001x over previous
//
#include <hip/hip_runtime.h>
#include <hip/hip_bf16.h>

#define NROW 4096      // 2B
#define HALFB 2048     // B
#define CDIM 1024
#define INV_T 2.0f     // 1/0.5
#define NBLK 32        // NROW / 128
#define NTRI 528       // NBLK*(NBLK+1)/2
#define NT 8           // K-tiles of 128
#define RB 512         // bytes per row in fp4 (1024 * 4bit)
#define SCALE_E8M0 122 // 2^-5: data stored as x*32 in e2m1; scale applied on A and B

typedef __attribute__((ext_vector_type(4))) float f32x4;
typedef __attribute__((ext_vector_type(8))) int i32x8;

// round-to-nearest e2m1 encode of q (|q| clamped to 6)
__device__ __forceinline__ unsigned enc_fp4(float q) {
    const unsigned s = q < 0.f ? 8u : 0u;
    const float a = fabsf(q);
    unsigned m;
    if (a < 1.25f) {
        if (a < 0.25f)      m = 0;   // 0.0
        else if (a < 0.75f) m = 1;   // 0.5
        else                m = 2;   // 1.0
    } else if (a < 2.5f) {
        m = (a < 1.75f) ? 3u : 4u;   // 1.5 : 2
    } else {
        if (a < 3.5f)       m = 5;   // 3
        else if (a < 5.0f)  m = 6;   // 4
        else                m = 7;   // 6
    }
    return s | m;
}

// ---------------- Kernel 1: row L2-normalize + fp4(e2m1) pack (+ zero den) ----------------
// q = 32 * x / ||x|| ~ N(0,1); stored e2m1, dequant by 2^-5 inside the MFMA.
__global__ __launch_bounds__(256) void normalize_kernel(
        const float* __restrict__ z1, const float* __restrict__ z2,
        unsigned short* __restrict__ zb4, float* __restrict__ den) {
    const int row = blockIdx.x;
    const int t = threadIdx.x;
    if (row < 16) den[row * 256 + t] = 0.f;   // NROW = 16*256; gemm is stream-ordered after
    const float* src = (row < HALFB) ? (z1 + (size_t)row * CDIM)
                                     : (z2 + (size_t)(row - HALFB) * CDIM);
    float4 v = ((const float4*)src)[t];
    float ss = v.x * v.x + v.y * v.y + v.z * v.z + v.w * v.w;
    #pragma unroll
    for (int off = 1; off < 64; off <<= 1) ss += __shfl_xor(ss, off);
    __shared__ float wsum[4];
    const int lane = t & 63, wv = t >> 6;
    if (lane == 0) wsum[wv] = ss;
    __syncthreads();
    const float tot = wsum[0] + wsum[1] + wsum[2] + wsum[3];
    const float scale = 32.0f / fmaxf(sqrtf(tot), 1e-12f);
    const unsigned c0 = enc_fp4(v.x * scale);
    const unsigned c1 = enc_fp4(v.y * scale);
    const unsigned c2 = enc_fp4(v.z * scale);
    const unsigned c3 = enc_fp4(v.w * scale);
    zb4[(size_t)row * 256 + t] = (unsigned short)(c0 | (c1 << 4) | (c2 << 8) | (c3 << 12));
}

// ---------------- Kernel 2: upper-triangle MX-fp4 GEMM + exp + row/col sums + pos ----------------
// 528 blocks (triangle of 128^2 tiles), 256 thr (4 waves 2x2, per-wave 64x64).
// K: 8 tiles of BK=128 via mfma_scale FMT=fp4 (cbsz=blgp=4), uniform scale 2^-5.
// T3-minimum 2-phase pipeline: LDS dbuf 2x16KB (32KB total, no occupancy cost at
// 2 blocks/CU); STAGE(t+1) issued BEFORE compute(t); one vmcnt(0)+barrier per
// iter -> the ~500cy L2 stage latency hides under ds_read+MFMA (~400cy).
// Swizzle: 16B chunk c of row r holds global chunk c^((r>>1)&3) (source-side,
// linear LDS dest; same XOR on ds_read). Residual 2-way bank alias = free.
// Rule #20 / R8 lesson: b[4] in regs, a JIT per m, acc compile-time indexed.
__global__ __launch_bounds__(256) void gemm_den_kernel(
        const unsigned char* __restrict__ zb4, float* __restrict__ den,
        float* __restrict__ pos) {
    __shared__ __align__(16) unsigned char As[2][128 * 64];
    __shared__ __align__(16) unsigned char Bs[2][128 * 64];

    // XCD swizzle (528 = 8*66, bijective), then triangle decode
    const int orig = blockIdx.x;
    int swz = (orig & 7) * (NTRI / 8) + (orig >> 3);
    int bi = 0, rem = swz;
    while (rem >= NBLK - bi) { rem -= NBLK - bi; ++bi; }
    const int bj = bi + rem;
    const int i0 = bi * 128, j0 = bj * 128;
    const bool diag = (bi == bj);
    const bool is_pos = (bj == bi + 16);   // holds S[i, i+B] on its tile diagonal

    const int tid = threadIdx.x;
    const int wave = tid >> 6, lane = tid & 63;
    const int wr = wave >> 1, wc = wave & 1;

    f32x4 acc[4][4];
    #pragma unroll
    for (int m = 0; m < 4; m++)
        #pragma unroll
        for (int n = 0; n < 4; n++) acc[m][n] = (f32x4){0.f, 0.f, 0.f, 0.f};

    // staging geometry: one gload_lds = 16 rows x 64B; lane: row=lane>>2, chunk=lane&3
    const int srow = lane >> 2;                            // 0..15
    const int schunk = (lane & 3) ^ ((srow >> 1) & 3);     // pre-swizzled source chunk

    const int l15 = lane & 15, ks = lane >> 4;

    auto stage = [&](int buf, int t) {
        const int kb = t * 64;
        #pragma unroll
        for (int c = 0; c < 2; ++c) {
            const int r0 = wave * 32 + c * 16;             // wave-uniform row base
            const unsigned char* ga =
                zb4 + (size_t)(i0 + r0 + srow) * RB + kb + schunk * 16;
            __builtin_amdgcn_global_load_lds(
                (const __attribute__((address_space(1))) void*)ga,
                (__attribute__((address_space(3))) void*)(As[buf] + r0 * 64),
                16, 0, 0);
            // diag blocks: j0 == i0 -> same panel staged twice (uniform schedule)
            const unsigned char* gb =
                zb4 + (size_t)(j0 + r0 + srow) * RB + kb + schunk * 16;
            __builtin_amdgcn_global_load_lds(
                (const __attribute__((address_space(1))) void*)gb,
                (__attribute__((address_space(3))) void*)(Bs[buf] + r0 * 64),
                16, 0, 0);
        }
    };

    // prologue
    stage(0, 0);
    asm volatile("s_waitcnt vmcnt(0)" ::: "memory");
    __builtin_amdgcn_s_barrier();

    #pragma unroll
    for (int t = 0; t < NT; ++t) {
        const int buf = t & 1;
        if (t + 1 < NT) stage(buf ^ 1, t + 1);   // issue-early: hides under compute

        i32x8 b[4];
        #pragma unroll
        for (int n = 0; n < 4; ++n) {
            const int r = wc * 64 + n * 16 + l15;
            const int slot = ks ^ ((r >> 1) & 3);
            const int4 w = *(const int4*)(Bs[buf] + r * 64 + slot * 16);
            b[n] = (i32x8){w.x, w.y, w.z, w.w, 0, 0, 0, 0};
        }
        __builtin_amdgcn_s_setprio(1);
        #pragma unroll
        for (int m = 0; m < 4; ++m) {
            const int r = wr * 64 + m * 16 + l15;
            const int slot = ks ^ ((r >> 1) & 3);
            const int4 w = *(const int4*)(As[buf] + r * 64 + slot * 16);
            const i32x8 a = (i32x8){w.x, w.y, w.z, w.w, 0, 0, 0, 0};
            #pragma unroll
            for (int n = 0; n < 4; ++n)
                acc[m][n] = __builtin_amdgcn_mfma_scale_f32_16x16x128_f8f6f4(
                    a, b[n], acc[m][n],
                    4 /*cbsz: A=fp4*/, 4 /*blgp: B=fp4*/,
                    0, SCALE_E8M0, 0, SCALE_E8M0);
        }
        __builtin_amdgcn_s_setprio(0);
        if (t + 1 < NT) {
            asm volatile("s_waitcnt vmcnt(0)" ::: "memory");  // next buf staged
            __builtin_amdgcn_s_barrier();
        }
    }

    // ---- positives: tiles bj == bi+16 (bi<16) hold S[i, i+B] on their diagonal
    if (is_pos && wr == wc) {
        #pragma unroll
        for (int m = 0; m < 4; ++m) {
            #pragma unroll
            for (int r = 0; r < 4; ++r) {
                if (l15 == ks * 4 + r)
                    pos[i0 + wr * 64 + m * 16 + l15] = acc[m][m][r];
            }
        }
    }

    // ---- epilogue: e = exp(2*s); row-sums -> den[i-panel]; col-sums -> den[j-panel]
    float cs[4] = {0.f, 0.f, 0.f, 0.f};
    #pragma unroll
    for (int m = 0; m < 4; ++m) {
        #pragma unroll
        for (int r = 0; r < 4; ++r) {
            float rs = 0.f;
            #pragma unroll
            for (int n = 0; n < 4; ++n) {
                const float e = __expf(INV_T * acc[m][n][r]);
                rs += e;
                cs[n] += e;
            }
            rs += __shfl_xor(rs, 1);
            rs += __shfl_xor(rs, 2);
            rs += __shfl_xor(rs, 4);
            rs += __shfl_xor(rs, 8);
            if (l15 == 0) {
                const int grow = i0 + wr * 64 + m * 16 + ks * 4 + r;
                atomicAdd(&den[grow], rs);
            }
        }
    }
    if (!diag) {
        #pragma unroll
        for (int n = 0; n < 4; ++n) {
            float c = cs[n];
            c += __shfl_xor(c, 16);
            c += __shfl_xor(c, 32);
            if (lane < 16) {
                const int gcol = j0 + wc * 64 + n * 16 + lane;
                atomicAdd(&den[gcol], c);
            }
        }
    }
}

// ---------------- Kernel 3: final loss ----------------
__global__ __launch_bounds__(256) void loss_kernel(
        const float* __restrict__ den, const float* __restrict__ pos,
        float* __restrict__ out) {
    const float E2 = 7.3890560989306495f;  // exp(2) = diagonal term
    const int tid = threadIdx.x;
    float acc = 0.f;
    for (int i = tid; i < NROW; i += 256)
        acc += INV_T * pos[i & (HALFB - 1)] - logf(den[i] - E2);
    #pragma unroll
    for (int off = 1; off < 64; off <<= 1) acc += __shfl_xor(acc, off);
    __shared__ float wsum[4];
    const int lane = tid & 63, wv = tid >> 6;
    if (lane == 0) wsum[wv] = acc;
    __syncthreads();
    if (tid == 0) out[0] = -(wsum[0] + wsum[1] + wsum[2] + wsum[3]) * (1.0f / NROW);
}

extern "C" void kernel_launch(void* const* d_in, const int* in_sizes, int n_in,
                              void* d_out, int out_size, void* d_ws, size_t ws_size,
                              hipStream_t stream) {
    const float* z1 = (const float*)d_in[0];
    const float* z2 = (const float*)d_in[1];
    float* out = (float*)d_out;

    unsigned short* zb4 = (unsigned short*)d_ws;                     // 2 MB (fp4)
    float* den = (float*)((char*)d_ws + (size_t)NROW * RB);          // 16 KB
    float* pos = den + NROW;                                         // 8 KB

    normalize_kernel<<<NROW, 256, 0, stream>>>(z1, z2, zb4, den);
    gemm_den_kernel<<<NTRI, 256, 0, stream>>>((const unsigned char*)zb4, den, pos);
    loss_kernel<<<1, 256, 0, stream>>>(den, pos, out);
}